// Round 14
// baseline (413.625 us; speedup 1.0000x reference)
//
#include <hip/hip_runtime.h>
#include <cstddef>
#include <cstdint>
#include <cmath>

// Problem constants
#define BDIM  64
#define SDIM  1024
#define DDIM  200
#define DPAD  224            // 7 x 32 k-steps, 14 x 16 n-tiles
#define PSTRIDE 232          // global row stride of p_bf (== LDS K stride, bank-friendly)
#define CDIM  31
#define NSTACK 2
#define EPS   1e-5f
#define LN_N  204800.0f      // 1024*200 elements per batch LN plane
#define PREP_BLOCKS 196      // ceil(224*224/256)

typedef __attribute__((ext_vector_type(8))) short short8;
typedef __attribute__((ext_vector_type(4))) short short4_t;
typedef __attribute__((ext_vector_type(4))) float f32x4;

__device__ __forceinline__ short f2bf(float f) {
    union { float f; unsigned u; } v; v.f = f;
    unsigned r = v.u + 0x7FFFu + ((v.u >> 16) & 1u);   // RNE
    return (short)(r >> 16);
}
__device__ __forceinline__ float bf2f(short s) {
    union { unsigned u; float f; } v; v.u = ((unsigned)(unsigned short)s) << 16;
    return v.f;
}
__device__ __forceinline__ unsigned cvtpk_bf16(float a, float b) {
    unsigned r;
    asm volatile("v_cvt_pk_bf16_f32 %0, %1, %2" : "=v"(r) : "v"(a), "v"(b));
    return r;
}
__device__ __forceinline__ void gload_lds16(const short* g, short* l) {
    __builtin_amdgcn_global_load_lds(
        (const __attribute__((address_space(1))) void*)g,
        (__attribute__((address_space(3))) void*)l, 16, 0, 0);
}

// -------- fused prep (weights/biases/colsums) + embed (+ parts zeroing) --------
__global__ void prep_embed_kernel(const int* __restrict__ x, const float* __restrict__ embed,
                                  const float* __restrict__ pos,
                                  const float* __restrict__ Wp, const float* __restrict__ bp,
                                  const float* __restrict__ Wm, const float* __restrict__ bm,
                                  const float* __restrict__ W1, const float* __restrict__ b1,
                                  const float* __restrict__ W2, const float* __restrict__ b2,
                                  short* __restrict__ WtP, short* __restrict__ WtM,
                                  short* __restrict__ Wt1, short* __restrict__ Wt2,
                                  float* __restrict__ bpP, float* __restrict__ bmP,
                                  float* __restrict__ b1P, float* __restrict__ b2P,
                                  float* __restrict__ csP, float* __restrict__ cs1,
                                  short* __restrict__ h, float* __restrict__ parts)
{
    if (blockIdx.x < PREP_BLOCKS) {
        int idx = blockIdx.x * 256 + threadIdx.x;
        if (idx >= DPAD * DPAD) return;
        int n = idx / DPAD, k = idx - n * DPAD;
        bool valid = (n < DDIM) && (k < DDIM);
        WtP[idx] = valid ? f2bf(Wp[(size_t)k * DDIM + n]) : 0;
        Wt1[idx] = valid ? f2bf(W1[(size_t)k * DDIM + n]) : 0;
        Wt2[idx] = valid ? f2bf(W2[(size_t)k * DDIM + n]) : 0;
        float s = 0.f;
        if (valid) {
            #pragma unroll
            for (int blk = 0; blk < 8; ++blk)
                s += Wm[(size_t)(blk * DDIM + k) * DDIM + n];
        }
        WtM[idx] = valid ? f2bf(s) : 0;
        if (idx < DPAD) {
            bpP[idx] = idx < DDIM ? bp[idx] : 0.f;
            bmP[idx] = idx < DDIM ? bm[idx] : 0.f;
            b1P[idx] = idx < DDIM ? b1[idx] : 0.f;
            b2P[idx] = idx < DDIM ? b2[idx] : 0.f;
            float sp = 0.f, s1 = 0.f;
            if (idx < DDIM) {
                for (int kk = 0; kk < DDIM; ++kk) {
                    sp += bf2f(f2bf(Wp[(size_t)kk * DDIM + idx]));
                    s1 += bf2f(f2bf(W1[(size_t)kk * DDIM + idx]));
                }
            }
            csP[idx] = sp;
            cs1[idx] = s1;
        }
        return;
    }

    const int eb = blockIdx.x - PREP_BLOCKS;       // embed part: 2048 blocks
    if (eb == 0) {
        for (int i = threadIdx.x; i < 4 * BDIM * 2; i += 256) parts[i] = 0.f;
    }
    const int total = BDIM * SDIM * (DPAD / 4);
    for (int i = eb * 256 + threadIdx.x; i < total; i += 2048 * 256) {
        const int row = i / (DPAD / 4);
        const int n0  = (i - row * (DPAD / 4)) * 4;
        short4_t o;
        if (n0 >= DDIM) {
            o[0] = o[1] = o[2] = o[3] = 0;
        } else {
            const int s = row & (SDIM - 1);
            const int tok = x[row];
            const float4 e  = *(const float4*)(embed + (size_t)tok * DDIM + n0);
            const float4 p4 = *(const float4*)(pos + (size_t)s * DDIM + n0);
            o[0] = f2bf(e.x + p4.x); o[1] = f2bf(e.y + p4.y);
            o[2] = f2bf(e.z + p4.z); o[3] = f2bf(e.w + p4.w);
        }
        *(short4_t*)(h + (size_t)row * DPAD + n0) = o;
    }
}

// ---------------- bf16 MFMA GEMM: ring-3 Wt staging, counted vmcnt (T3/T4) ------
// out[M,224] = LN?(act) @ Wt^T + bias (+ LN?(res)) (+relu) (+stats) (+pt write)
// act loads in compile-time slice array afr[7][2] (full unroll -> no register
// copies -> no forced waits on fresh loads). 2-deep on act AND stage; end-of-iter
// vmcnt retires exactly through stage(ks+1): per-wave vmcnt(6)/(5).
#define WSLICE 7168   // 224*32 shorts per buffer
__global__ __launch_bounds__(256, 3)
void gemm_bf(const short* __restrict__ act, const float* __restrict__ actParts,
             const short* __restrict__ Wt, const float* __restrict__ bias,
             const float* __restrict__ csW,
             const short* __restrict__ res, const float* __restrict__ resParts,
             short* __restrict__ out, short* __restrict__ pt,
             float* __restrict__ parts, int doRelu, int outStride)
{
    __shared__ short WB[3][WSLICE];   // 43008 B

    const int tid  = threadIdx.x;
    const int wave = tid >> 6, lane = tid & 63;
    const int lo   = lane & 15, hi = lane >> 4;
    const int mblk = blockIdx.x * 128;
    const int m0   = mblk + wave * 32;

    // per-wave chunk count: waves 0,1 -> 4 chunks; waves 2,3 -> 3 chunks
    auto stage = [&](int ks, int buf) {
        for (int c = wave; c < 14; c += 4) {
            int row = c * 16 + (lane >> 2);
            int kc  = (lane & 3) ^ ((row >> 1) & 3);
            gload_lds16(Wt + (size_t)row * DPAD + ks * 32 + kc * 8,
                        &WB[buf][c * 512 + lane * 8]);
        }
    };

    f32x4 acc[2][14];
    #pragma unroll
    for (int mt = 0; mt < 2; ++mt)
        #pragma unroll
        for (int nt = 0; nt < 14; ++nt) acc[mt][nt] = (f32x4){0.f, 0.f, 0.f, 0.f};

    short8 afr[7][2];   // act slice registers, compile-time indexed (full unroll)

    #pragma unroll
    for (int mt = 0; mt < 2; ++mt)
        afr[0][mt] = *(const short8*)(act + (size_t)(m0 + mt * 16 + lo) * DPAD + hi * 8);
    stage(0, 0);
    #pragma unroll
    for (int mt = 0; mt < 2; ++mt)
        afr[1][mt] = *(const short8*)(act + (size_t)(m0 + mt * 16 + lo) * DPAD + 32 + hi * 8);
    stage(1, 1);
    // retire afr0 + stage0; leave afr1(2) + stage1(4|3) in flight
    if (wave < 2) asm volatile("s_waitcnt vmcnt(6)" ::: "memory");
    else          asm volatile("s_waitcnt vmcnt(5)" ::: "memory");
    __builtin_amdgcn_s_barrier();

    #pragma unroll
    for (int ks = 0; ks < 7; ++ks) {
        const int cur = ks % 3;
        if (ks < 5) {
            #pragma unroll
            for (int mt = 0; mt < 2; ++mt)
                afr[ks + 2][mt] = *(const short8*)(act + (size_t)(m0 + mt * 16 + lo) * DPAD
                                                   + (ks + 2) * 32 + hi * 8);
            stage(ks + 2, (ks + 2) % 3);
        }

        #pragma unroll
        for (int nt = 0; nt < 14; ++nt) {
            int brow = nt * 16 + lo;
            short8 bf_ = *(const short8*)&WB[cur][brow * 32
                                                  + ((hi * 8) ^ (((brow >> 1) & 3) << 3))];
            acc[0][nt] = __builtin_amdgcn_mfma_f32_16x16x32_bf16(afr[ks][0], bf_, acc[0][nt], 0, 0, 0);
            acc[1][nt] = __builtin_amdgcn_mfma_f32_16x16x32_bf16(afr[ks][1], bf_, acc[1][nt], 0, 0, 0);
        }

        if (ks < 5) {
            // retire through stage(ks+1); leave afr[ks+2](2)+stage(ks+2)(4|3)
            if (wave < 2) asm volatile("s_waitcnt vmcnt(6)" ::: "memory");
            else          asm volatile("s_waitcnt vmcnt(5)" ::: "memory");
            __builtin_amdgcn_s_barrier();
        } else if (ks == 5) {
            asm volatile("s_waitcnt vmcnt(0)" ::: "memory");   // stage(6)+afr[6] (1.5 iters old)
            __builtin_amdgcn_s_barrier();
        }
    }

    const int bb = mblk >> 10;                 // batch (blocks never straddle)
    float inv_a = 1.f, corr = 0.f;
    if (actParts) {
        float mean = actParts[bb * 2] / LN_N;
        inv_a = rsqrtf(actParts[bb * 2 + 1] / LN_N - mean * mean + EPS);
        corr = mean * inv_a;
    }
    float mean_r = 0.f, inv_r = 1.f;
    if (resParts) {
        mean_r = resParts[bb * 2] / LN_N;
        inv_r = rsqrtf(resParts[bb * 2 + 1] / LN_N - mean_r * mean_r + EPS);
    }

    float s = 0.f, s2 = 0.f;
    #pragma unroll
    for (int mt = 0; mt < 2; ++mt) {
        #pragma unroll
        for (int nt = 0; nt < 14; ++nt) {
            const int n = nt * 16 + lo;
            const float bn = bias[n];
            const float cw = actParts ? csW[n] : 0.f;
            float v[4];
            #pragma unroll
            for (int r = 0; r < 4; ++r)
                v[r] = acc[mt][nt][r] * inv_a + bn - corr * cw;
            if (res) {
                #pragma unroll
                for (int r = 0; r < 4; ++r) {
                    int m = m0 + mt * 16 + hi * 4 + r;
                    v[r] += (bf2f(res[(size_t)m * DPAD + n]) - mean_r) * inv_r;
                }
            }
            if (doRelu)
                #pragma unroll
                for (int r = 0; r < 4; ++r) v[r] = fmaxf(v[r], 0.f);
            if (n >= DDIM)
                #pragma unroll
                for (int r = 0; r < 4; ++r) v[r] = 0.f;
            if (parts)
                #pragma unroll
                for (int r = 0; r < 4; ++r) { s += v[r]; s2 = fmaf(v[r], v[r], s2); }
            short4_t o4;
            #pragma unroll
            for (int r = 0; r < 4; ++r) o4[r] = f2bf(v[r]);
            #pragma unroll
            for (int r = 0; r < 4; ++r) {
                int m = m0 + mt * 16 + hi * 4 + r;
                out[(size_t)m * outStride + n] = o4[r];
            }
            if (pt && nt < 13) {
                const int sloc = (m0 + mt * 16 + hi * 4) & (SDIM - 1);
                *(short4_t*)(pt + ((size_t)bb * DPAD + n) * SDIM + sloc) = o4;
            }
        }
    }

    if (parts) {
        __shared__ float rs[4], rq[4];
        #pragma unroll
        for (int off = 32; off; off >>= 1) {
            s  += __shfl_down(s, off);
            s2 += __shfl_down(s2, off);
        }
        if (lane == 0) { rs[wave] = s; rq[wave] = s2; }
        __syncthreads();
        if (tid == 0) {
            atomicAdd(&parts[bb * 2],     rs[0] + rs[1] + rs[2] + rs[3]);
            atomicAdd(&parts[bb * 2 + 1], rq[0] + rq[1] + rq[2] + rq[3]);
        }
    }
}

// ---------------- fused FFN: out = relu(LN(act)@W1+b1)@W2 + b2 + LN(act) --------
// Ring-3 staging over 14 W-slices (W1 k=0..6 then W2 k=0..6), counted vmcnt.
#define Y1S 232
__global__ __launch_bounds__(256, 2)
void ffn_bf(const short* __restrict__ act, const float* __restrict__ actParts,
            const float* __restrict__ csW1,
            const short* __restrict__ Wt1, const float* __restrict__ b1,
            const short* __restrict__ Wt2, const float* __restrict__ b2,
            short* __restrict__ out, float* __restrict__ parts)
{
    __shared__ short WB[3][WSLICE];   // 43008 B
    __shared__ short Y1[64 * Y1S];    // 29696 B   (total 72704 -> 2 blocks/CU)

    const int tid  = threadIdx.x;
    const int wave = tid >> 6, lane = tid & 63;
    const int lo   = lane & 15, hi = lane >> 4;
    const int mblk = blockIdx.x * 64;
    const int m0   = mblk + wave * 16;
    const int bb   = mblk >> 10;

    // slice j: 0..6 -> W1 k=j ; 7..13 -> W2 k=j-7 ; buffer j%3
    auto stageJ = [&](int j) {
        const short* W = (j < 7) ? Wt1 : Wt2;
        const int kk = (j < 7) ? j : j - 7;
        const int buf = j % 3;
        for (int c = wave; c < 14; c += 4) {
            int row = c * 16 + (lane >> 2);
            int kc  = (lane & 3) ^ ((row >> 1) & 3);
            gload_lds16(W + (size_t)row * DPAD + kk * 32 + kc * 8,
                        &WB[buf][c * 512 + lane * 8]);
        }
    };

    const float mean_a = actParts[bb * 2] / LN_N;
    const float inv_a  = rsqrtf(actParts[bb * 2 + 1] / LN_N - mean_a * mean_a + EPS);
    const float corr   = mean_a * inv_a;

    // ---- stage 1: y1 = relu(LN(act)@W1 + b1) -> Y1 ----
    f32x4 acc[14];
    #pragma unroll
    for (int nt = 0; nt < 14; ++nt) acc[nt] = (f32x4){0.f, 0.f, 0.f, 0.f};

    short8 af = *(const short8*)(act + (size_t)(m0 + lo) * DPAD + hi * 8);
    short8 afn;
    stageJ(0);
    stageJ(1);
    asm volatile("s_waitcnt vmcnt(3)" ::: "memory");
    __builtin_amdgcn_s_barrier();

    #pragma unroll
    for (int ks = 0; ks < 7; ++ks) {
        const int cur = ks % 3;
        if (ks < 6)
            afn = *(const short8*)(act + (size_t)(m0 + lo) * DPAD + (ks + 1) * 32 + hi * 8);
        stageJ(ks + 2);   // slices 2..8 (8 = W2 k=1)
        #pragma unroll
        for (int nt = 0; nt < 14; ++nt) {
            int brow = nt * 16 + lo;
            short8 bf_ = *(const short8*)&WB[cur][brow * 32
                                                  + ((hi * 8) ^ (((brow >> 1) & 3) << 3))];
            acc[nt] = __builtin_amdgcn_mfma_f32_16x16x32_bf16(af, bf_, acc[nt], 0, 0, 0);
        }
        if (ks < 6) {
            asm volatile("s_waitcnt vmcnt(5)" ::: "memory");
            __builtin_amdgcn_s_barrier();
            af = afn;
        }
    }

    // epilogue 1: bias + LN-colsum correction + relu -> Y1 (bf16)
    #pragma unroll
    for (int nt = 0; nt < 14; ++nt) {
        const int n = nt * 16 + lo;
        const float bn = b1[n];
        const float cw = csW1[n];
        #pragma unroll
        for (int r = 0; r < 4; ++r) {
            float v = fmaxf(acc[nt][r] * inv_a + bn - corr * cw, 0.f);
            Y1[(wave * 16 + hi * 4 + r) * Y1S + n] = f2bf(v);
        }
    }
    __syncthreads();   // Y1 visible; drains in-flight W2 slices 7,8 (once)

    // ---- stage 2: out = Y1 @ W2 + b2 + LN(act) ----
    #pragma unroll
    for (int nt = 0; nt < 14; ++nt) acc[nt] = (f32x4){0.f, 0.f, 0.f, 0.f};

    #pragma unroll
    for (int j = 7; j < 14; ++j) {
        const int cur = j % 3;
        if (j < 12) stageJ(j + 2);    // slices 9..13
        short8 a2 = *(const short8*)&Y1[(wave * 16 + lo) * Y1S + (j - 7) * 32 + hi * 8];
        #pragma unroll
        for (int nt = 0; nt < 14; ++nt) {
            int brow = nt * 16 + lo;
            short8 bf_ = *(const short8*)&WB[cur][brow * 32
                                                  + ((hi * 8) ^ (((brow >> 1) & 3) << 3))];
            acc[nt] = __builtin_amdgcn_mfma_f32_16x16x32_bf16(a2, bf_, acc[nt], 0, 0, 0);
        }
        if (j < 12)       asm volatile("s_waitcnt vmcnt(3)" ::: "memory");
        else if (j == 12) asm volatile("s_waitcnt vmcnt(0)" ::: "memory");
        if (j < 13) __builtin_amdgcn_s_barrier();
    }

    // epilogue 2: + b2 + LN(act) residual + stats -> out
    float s = 0.f, s2 = 0.f;
    #pragma unroll
    for (int nt = 0; nt < 14; ++nt) {
        const int n = nt * 16 + lo;
        const float bn = b2[n];
        float v[4];
        #pragma unroll
        for (int r = 0; r < 4; ++r) {
            int m = m0 + hi * 4 + r;
            v[r] = acc[nt][r] + bn + (bf2f(act[(size_t)m * DPAD + n]) - mean_a) * inv_a;
        }
        if (n >= DDIM)
            #pragma unroll
            for (int r = 0; r < 4; ++r) v[r] = 0.f;
        #pragma unroll
        for (int r = 0; r < 4; ++r) { s += v[r]; s2 = fmaf(v[r], v[r], s2); }
        #pragma unroll
        for (int r = 0; r < 4; ++r) {
            int m = m0 + hi * 4 + r;
            out[(size_t)m * DPAD + n] = f2bf(v[r]);
        }
    }

    {
        __shared__ float rs[4], rq[4];
        #pragma unroll
        for (int off = 32; off; off >>= 1) {
            s  += __shfl_down(s, off);
            s2 += __shfl_down(s2, off);
        }
        if (lane == 0) { rs[wave] = s; rq[wave] = s2; }
        __syncthreads();
        if (tid == 0) {
            atomicAdd(&parts[bb * 2],     rs[0] + rs[1] + rs[2] + rs[3]);
            atomicAdd(&parts[bb * 2 + 1], rq[0] + rq[1] + rq[2] + rq[3]);
        }
    }
}

// ---------------- fused MFMA flash attention (proven round-9/11 version) --------
__global__ __launch_bounds__(256, 2)
void attn_kernel(const short* __restrict__ pbf, const short* __restrict__ pt,
                 short* __restrict__ c, float qscale)
{
    __shared__ short Kbuf[2][7680];   // 32 x 232 (+pad)
    __shared__ short Vbuf[2][6656];   // 208 x 32 (col-xor-swizzled)

    const int bid = blockIdx.x;
    const int wg  = (bid & 7) * 64 + (bid >> 3);   // XCD chunk swizzle
    const int b   = wg >> 3;
    const int q0  = (wg & 7) * 128;

    const int tid  = threadIdx.x;
    const int wave = tid >> 6;
    const int lane = tid & 63;
    const int lo   = lane & 15;
    const int hi   = lane >> 4;

    const short* pb  = pbf + (size_t)b * SDIM * PSTRIDE;
    const short* ptb = pt  + (size_t)b * DPAD * SDIM;

    auto stage = [&](int kt2, int bufIdx) {
        const short* ks = pb + (size_t)kt2 * 32 * PSTRIDE + lane * 8;
        #pragma unroll
        for (int i = 0; i < 15; ++i)
            gload_lds16(ks + i * 512, &Kbuf[bufIdx][i * 512]);
        #pragma unroll
        for (int i = 0; i < 13; ++i) {
            int e = i * 512 + lane * 8;
            int d = e >> 5;
            int cc = (e & 31) ^ (((d >> 1) & 3) << 3);
            gload_lds16(ptb + (size_t)d * SDIM + kt2 * 32 + cc, &Vbuf[bufIdx][i * 512]);
        }
    };

    short8 qf[2][7];
    #pragma unroll
    for (int qt = 0; qt < 2; ++qt)
        #pragma unroll
        for (int ks = 0; ks < 7; ++ks) {
            short8 q = *(const short8*)(pb + (size_t)(q0 + wave * 32 + qt * 16 + lo) * PSTRIDE
                                        + ks * 32 + hi * 8);
            short8 qs;
            #pragma unroll
            for (int j = 0; j < 8; ++j) qs[j] = f2bf(bf2f(q[j]) * qscale);
            qf[qt][ks] = qs;
        }

    f32x4 o[2][13];
    float m[2], ell[2];
    #pragma unroll
    for (int qt = 0; qt < 2; ++qt) {
        #pragma unroll
        for (int n = 0; n < 13; ++n) o[qt][n] = (f32x4){0.f, 0.f, 0.f, 0.f};
        m[qt] = -1e30f; ell[qt] = 0.f;
    }

    if (wave == 0) stage(0, 0);
    __syncthreads();

    for (int kt = 0; kt < 32; ++kt) {
        const int cur = kt & 1;
        if (kt < 31 && wave == ((kt + 1) & 3)) stage(kt + 1, cur ^ 1);

        f32x4 sacc[2][2];
        #pragma unroll
        for (int qt = 0; qt < 2; ++qt)
            #pragma unroll
            for (int t = 0; t < 2; ++t) sacc[qt][t] = (f32x4){0.f, 0.f, 0.f, 0.f};
        __builtin_amdgcn_s_setprio(1);
        #pragma unroll
        for (int t = 0; t < 2; ++t)
            #pragma unroll
            for (int ks = 0; ks < 7; ++ks) {
                short8 kf = *(const short8*)(&Kbuf[cur][(t * 16 + lo) * PSTRIDE + ks * 32 + hi * 8]);
                sacc[0][t] = __builtin_amdgcn_mfma_f32_16x16x32_bf16(kf, qf[0][ks], sacc[0][t], 0, 0, 0);
                sacc[1][t] = __builtin_amdgcn_mfma_f32_16x16x32_bf16(kf, qf[1][ks], sacc[1][t], 0, 0, 0);
            }
        __builtin_amdgcn_s_setprio(0);

        short8 pa[2];
        #pragma unroll
        for (int qt = 0; qt < 2; ++qt) {
            float mx = fmaxf(fmaxf(fmaxf(sacc[qt][0][0], sacc[qt][0][1]),
                                   fmaxf(sacc[qt][0][2], sacc[qt][0][3])),
                             fmaxf(fmaxf(sacc[qt][1][0], sacc[qt][1][1]),
                                   fmaxf(sacc[qt][1][2], sacc[qt][1][3])));
            mx = fmaxf(mx, __shfl_xor(mx, 16));
            mx = fmaxf(mx, __shfl_xor(mx, 32));
            if (__any(mx > m[qt] + 11.5f)) {          // T13 defer-max (log2 units)
                float mn = fmaxf(m[qt], mx);
                float al = exp2f(m[qt] - mn);
                m[qt] = mn; ell[qt] *= al;
                float alr[4];
                #pragma unroll
                for (int r = 0; r < 4; ++r) alr[r] = __shfl(al, hi * 4 + r);
                #pragma unroll
                for (int n = 0; n < 13; ++n)
                    #pragma unroll
                    for (int r = 0; r < 4; ++r) o[qt][n][r] *= alr[r];
            }
            float p[2][4]; float rsum = 0.f;
            #pragma unroll
            for (int t = 0; t < 2; ++t)
                #pragma unroll
                for (int r = 0; r < 4; ++r) {
                    p[t][r] = exp2f(sacc[qt][t][r] - m[qt]);
                    rsum += p[t][r];
                }
            rsum += __shfl_xor(rsum, 16);
            rsum += __shfl_xor(rsum, 32);
            ell[qt] += rsum;
            unsigned pk01_0 = cvtpk_bf16(p[0][0], p[0][1]);
            unsigned pk23_0 = cvtpk_bf16(p[0][2], p[0][3]);
            unsigned pk01_1 = cvtpk_bf16(p[1][0], p[1][1]);
            unsigned pk23_1 = cvtpk_bf16(p[1][2], p[1][3]);
            const int srcA = lo + ((hi & 1) * 2) * 16;
            const int srcB = srcA + 16;
            int a0 = __shfl((int)pk01_0, srcA), a1 = __shfl((int)pk01_1, srcA);
            int b0 = __shfl((int)pk23_0, srcA), b1 = __shfl((int)pk23_1, srcA);
            int c0 = __shfl((int)pk01_0, srcB), c1 = __shfl((int)pk01_1, srcB);
            int d0 = __shfl((int)pk23_0, srcB), d1 = __shfl((int)pk23_1, srcB);
            const bool thi = (hi >> 1) != 0;
            union { short8 s; int u[4]; } pu;
            pu.u[0] = thi ? a1 : a0;
            pu.u[1] = thi ? b1 : b0;
            pu.u[2] = thi ? c1 : c0;
            pu.u[3] = thi ? d1 : d0;
            pa[qt] = pu.s;
        }

        __builtin_amdgcn_s_setprio(1);
        #pragma unroll
        for (int n = 0; n < 13; ++n) {
            int d = n * 16 + lo;
            int addr = d * 32 + ((hi * 8) ^ (((d >> 1) & 3) << 3));
            short8 vf = *(const short8*)(&Vbuf[cur][addr]);
            o[0][n] = __builtin_amdgcn_mfma_f32_16x16x32_bf16(pa[0], vf, o[0][n], 0, 0, 0);
            o[1][n] = __builtin_amdgcn_mfma_f32_16x16x32_bf16(pa[1], vf, o[1][n], 0, 0, 0);
        }
        __builtin_amdgcn_s_setprio(0);

        __syncthreads();
    }

    #pragma unroll
    for (int qt = 0; qt < 2; ++qt) {
        float inv_l = 1.f / ell[qt];
        float invr[4];
        #pragma unroll
        for (int r = 0; r < 4; ++r) invr[r] = __shfl(inv_l, hi * 4 + r);
        #pragma unroll
        for (int n = 0; n < 13; ++n) {
            int dcol = n * 16 + lo;
            #pragma unroll
            for (int r = 0; r < 4; ++r) {
                size_t row = (size_t)b * SDIM + q0 + wave * 32 + qt * 16 + hi * 4 + r;
                c[row * DPAD + dcol] = f2bf(o[qt][n][r] * invr[r]);
            }
        }
        #pragma unroll
        for (int r = 0; r < 4; ++r) {
            size_t row = (size_t)b * SDIM + q0 + wave * 32 + qt * 16 + hi * 4 + r;
            c[row * DPAD + 208 + lo] = 0;
        }
    }
}

// ---------------- final: normalize row S-1 only + head ----------------
__global__ void final_kernel(const short* __restrict__ y, const float* __restrict__ parts,
                             const float* __restrict__ Wd, const float* __restrict__ bd,
                             float* __restrict__ out)
{
    const int b = blockIdx.x;
    const float sum = parts[b * 2], sq = parts[b * 2 + 1];
    const float mean = sum / LN_N;
    const float inv  = rsqrtf(sq / LN_N - mean * mean + EPS);
    __shared__ float hrow[DDIM];
    const short* row = y + ((size_t)b * SDIM + SDIM - 1) * DPAD;
    for (int d = threadIdx.x; d < DDIM; d += blockDim.x)
        hrow[d] = (bf2f(row[d]) - mean) * inv;
    __syncthreads();
    if (threadIdx.x < CDIM) {
        float acc = bd[threadIdx.x];
        for (int d = 0; d < DDIM; ++d)
            acc = fmaf(hrow[d], Wd[(size_t)d * CDIM + threadIdx.x], acc);
        out[(size_t)b * CDIM + threadIdx.x] = acc;
    }
}

extern "C" void kernel_launch(void* const* d_in, const int* in_sizes, int n_in,
                              void* d_out, int out_size, void* d_ws, size_t ws_size,
                              hipStream_t stream)
{
    const int*   x     = (const int*)  d_in[0];
    const float* embed = (const float*)d_in[1];
    const float* pos   = (const float*)d_in[2];
    const float* Wp    = (const float*)d_in[3];
    const float* bp    = (const float*)d_in[4];
    const float* Wm    = (const float*)d_in[5];
    const float* bm    = (const float*)d_in[6];
    const float* W1    = (const float*)d_in[7];
    const float* b1    = (const float*)d_in[8];
    const float* W2    = (const float*)d_in[9];
    const float* b2    = (const float*)d_in[10];
    const float* Wd    = (const float*)d_in[11];
    const float* bd    = (const float*)d_in[12];
    float* out = (float*)d_out;

    const size_t HB = (size_t)BDIM * SDIM * DPAD;     // 14,680,064 bf16 elems
    const size_t PB = (size_t)BDIM * SDIM * PSTRIDE;  // p_bf with stride 232

    short* h_bf  = (short*)d_ws;
    short* p_bf  = h_bf  + HB;
    short* pt    = p_bf  + PB;
    short* cb_bf = pt    + HB;
    short* yA    = cb_bf + HB;
    short* yB    = yA    + HB;
    short* WtP   = yB + HB;
    short* WtM   = WtP + DPAD * DPAD;
    short* Wt1   = WtM + DPAD * DPAD;
    short* Wt2   = Wt1 + DPAD * DPAD;
    float* bpP   = (float*)(Wt2 + DPAD * DPAD);
    float* bmP   = bpP + DPAD;
    float* b1P   = bmP + DPAD;
    float* b2P   = b1P + DPAD;
    float* csP   = b2P + DPAD;
    float* cs1   = csP + DPAD;
    float* parts = cs1 + DPAD;                        // 4 x 64 x 2 floats
    const size_t need = (size_t)((char*)(parts + 4 * BDIM * 2) - (char*)d_ws);
    if (ws_size < need) return;

    float* pA1 = parts;
    float* pB1 = parts + BDIM * 2;
    float* pA2 = parts + 2 * BDIM * 2;
    float* pB2 = parts + 3 * BDIM * 2;

    prep_embed_kernel<<<dim3(PREP_BLOCKS + 2048), dim3(256), 0, stream>>>(
        x, embed, pos, Wp, bp, Wm, bm, W1, b1, W2, b2,
        WtP, WtM, Wt1, Wt2, bpP, bmP, b1P, b2P, csP, cs1, h_bf, parts);

    const float qscale = 1.44269504f / sqrtf((float)DDIM);

    // stack 1
    gemm_bf<<<dim3(512), dim3(256), 0, stream>>>(h_bf, nullptr, WtP, bpP, nullptr,
                                                 nullptr, nullptr, p_bf, pt, nullptr, 0, PSTRIDE);
    attn_kernel<<<dim3(512), dim3(256), 0, stream>>>(p_bf, pt, cb_bf, qscale);
    gemm_bf<<<dim3(512), dim3(256), 0, stream>>>(cb_bf, nullptr, WtM, bmP, nullptr,
                                                 h_bf, nullptr, yA, nullptr, pA1, 0, DPAD);
    ffn_bf<<<dim3(1024), dim3(256), 0, stream>>>(yA, pA1, cs1, Wt1, b1P, Wt2, b2P, yB, pB1);
    // stack 2
    gemm_bf<<<dim3(512), dim3(256), 0, stream>>>(yB, pB1, WtP, bpP, csP,
                                                 nullptr, nullptr, p_bf, pt, nullptr, 0, PSTRIDE);
    attn_kernel<<<dim3(512), dim3(256), 0, stream>>>(p_bf, pt, cb_bf, qscale);
    gemm_bf<<<dim3(512), dim3(256), 0, stream>>>(cb_bf, nullptr, WtM, bmP, nullptr,
                                                 yB, pB1, h_bf, nullptr, pA2, 0, DPAD);
    ffn_bf<<<dim3(1024), dim3(256), 0, stream>>>(h_bf, pA2, cs1, Wt1, b1P, Wt2, b2P, yA, pB2);
    final_kernel<<<dim3(BDIM), dim3(64), 0, stream>>>(yA, pB2, Wd, bd, out);
}

// Round 15
// 379.991 us; speedup vs baseline: 1.0885x; 1.0885x over previous
//
#include <hip/hip_runtime.h>
#include <cstddef>
#include <cstdint>
#include <cmath>

// Problem constants
#define BDIM  64
#define SDIM  1024
#define DDIM  200
#define DPAD  224            // 7 x 32 k-steps, 14 x 16 n-tiles
#define WROWS 256            // padded Wt rows -> 16 uniform stage chunks
#define PSTRIDE 232          // global row stride of p_bf (== LDS K stride, bank-friendly)
#define CDIM  31
#define NSTACK 2
#define EPS   1e-5f
#define LN_N  204800.0f      // 1024*200 elements per batch LN plane
#define PREP_BLOCKS 224      // 256*224/256

typedef __attribute__((ext_vector_type(8))) short short8;
typedef __attribute__((ext_vector_type(4))) short short4_t;
typedef __attribute__((ext_vector_type(4))) float f32x4;

__device__ __forceinline__ short f2bf(float f) {
    union { float f; unsigned u; } v; v.f = f;
    unsigned r = v.u + 0x7FFFu + ((v.u >> 16) & 1u);   // RNE
    return (short)(r >> 16);
}
__device__ __forceinline__ float bf2f(short s) {
    union { unsigned u; float f; } v; v.u = ((unsigned)(unsigned short)s) << 16;
    return v.f;
}
__device__ __forceinline__ unsigned cvtpk_bf16(float a, float b) {
    unsigned r;
    asm volatile("v_cvt_pk_bf16_f32 %0, %1, %2" : "=v"(r) : "v"(a), "v"(b));
    return r;
}
__device__ __forceinline__ void gload_lds16(const short* g, short* l) {
    __builtin_amdgcn_global_load_lds(
        (const __attribute__((address_space(1))) void*)g,
        (__attribute__((address_space(3))) void*)l, 16, 0, 0);
}

// -------- fused prep (weights/biases/colsums) + embed (+ parts zeroing) --------
// Wt buffers are [256][224]: rows 224..255 zero (uniform 16-chunk staging).
__global__ void prep_embed_kernel(const int* __restrict__ x, const float* __restrict__ embed,
                                  const float* __restrict__ pos,
                                  const float* __restrict__ Wp, const float* __restrict__ bp,
                                  const float* __restrict__ Wm, const float* __restrict__ bm,
                                  const float* __restrict__ W1, const float* __restrict__ b1,
                                  const float* __restrict__ W2, const float* __restrict__ b2,
                                  short* __restrict__ WtP, short* __restrict__ WtM,
                                  short* __restrict__ Wt1, short* __restrict__ Wt2,
                                  float* __restrict__ bpP, float* __restrict__ bmP,
                                  float* __restrict__ b1P, float* __restrict__ b2P,
                                  float* __restrict__ csP, float* __restrict__ cs1,
                                  short* __restrict__ h, float* __restrict__ parts)
{
    if (blockIdx.x < PREP_BLOCKS) {
        int idx = blockIdx.x * 256 + threadIdx.x;
        if (idx >= WROWS * DPAD) return;
        int n = idx / DPAD, k = idx - n * DPAD;
        bool valid = (n < DDIM) && (k < DDIM);
        WtP[idx] = valid ? f2bf(Wp[(size_t)k * DDIM + n]) : 0;
        Wt1[idx] = valid ? f2bf(W1[(size_t)k * DDIM + n]) : 0;
        Wt2[idx] = valid ? f2bf(W2[(size_t)k * DDIM + n]) : 0;
        float s = 0.f;
        if (valid) {
            #pragma unroll
            for (int blk = 0; blk < 8; ++blk)
                s += Wm[(size_t)(blk * DDIM + k) * DDIM + n];
        }
        WtM[idx] = valid ? f2bf(s) : 0;
        if (idx < DPAD) {
            bpP[idx] = idx < DDIM ? bp[idx] : 0.f;
            bmP[idx] = idx < DDIM ? bm[idx] : 0.f;
            b1P[idx] = idx < DDIM ? b1[idx] : 0.f;
            b2P[idx] = idx < DDIM ? b2[idx] : 0.f;
            float sp = 0.f, s1 = 0.f;
            if (idx < DDIM) {
                for (int kk = 0; kk < DDIM; ++kk) {
                    sp += bf2f(f2bf(Wp[(size_t)kk * DDIM + idx]));
                    s1 += bf2f(f2bf(W1[(size_t)kk * DDIM + idx]));
                }
            }
            csP[idx] = sp;
            cs1[idx] = s1;
        }
        return;
    }

    const int eb = blockIdx.x - PREP_BLOCKS;       // embed part: 2048 blocks
    if (eb == 0) {
        for (int i = threadIdx.x; i < 4 * BDIM * 2; i += 256) parts[i] = 0.f;
    }
    const int total = BDIM * SDIM * (DPAD / 4);
    for (int i = eb * 256 + threadIdx.x; i < total; i += 2048 * 256) {
        const int row = i / (DPAD / 4);
        const int n0  = (i - row * (DPAD / 4)) * 4;
        short4_t o;
        if (n0 >= DDIM) {
            o[0] = o[1] = o[2] = o[3] = 0;
        } else {
            const int s = row & (SDIM - 1);
            const int tok = x[row];
            const float4 e  = *(const float4*)(embed + (size_t)tok * DDIM + n0);
            const float4 p4 = *(const float4*)(pos + (size_t)s * DDIM + n0);
            o[0] = f2bf(e.x + p4.x); o[1] = f2bf(e.y + p4.y);
            o[2] = f2bf(e.z + p4.z); o[3] = f2bf(e.w + p4.w);
        }
        *(short4_t*)(h + (size_t)row * DPAD + n0) = o;
    }
}

// ---------------- bf16 MFMA GEMM: ring-3 staging, uniform counted vmcnt ---------
// out[M,224] = LN?(act) @ Wt^T + bias (+ LN?(res)) (+relu) (+stats) (+pt write)
// 16 chunks/slice = 4 per wave (uniform). Waits (derived, in-order retirement):
// prologue vmcnt(4) [retire af+stage0]; iters vmcnt(6) [retire stage(ks+1),
// leave afn(2)+stage(ks+2)(4)]; ks=5 vmcnt(2) [retire stage6, leave afn6].
// af=afn after barrier = SSA rename under full unroll (no register-array blowup).
#define WSLICE 8192   // 256*32 shorts per buffer
__global__ __launch_bounds__(256, 3)
void gemm_bf(const short* __restrict__ act, const float* __restrict__ actParts,
             const short* __restrict__ Wt, const float* __restrict__ bias,
             const float* __restrict__ csW,
             const short* __restrict__ res, const float* __restrict__ resParts,
             short* __restrict__ out, short* __restrict__ pt,
             float* __restrict__ parts, int doRelu, int outStride)
{
    __shared__ short WB[3][WSLICE];   // 49152 B -> 3 blocks/CU

    const int tid  = threadIdx.x;
    const int wave = tid >> 6, lane = tid & 63;
    const int lo   = lane & 15, hi = lane >> 4;
    const int mblk = blockIdx.x * 128;
    const int m0   = mblk + wave * 32;

    auto stage = [&](int ks, int buf) {
        #pragma unroll
        for (int cc = 0; cc < 4; ++cc) {
            int c = wave + cc * 4;
            int row = c * 16 + (lane >> 2);
            int kc  = (lane & 3) ^ ((row >> 1) & 3);
            gload_lds16(Wt + (size_t)row * DPAD + ks * 32 + kc * 8,
                        &WB[buf][c * 512 + lane * 8]);
        }
    };

    f32x4 acc[2][14];
    #pragma unroll
    for (int mt = 0; mt < 2; ++mt)
        #pragma unroll
        for (int nt = 0; nt < 14; ++nt) acc[mt][nt] = (f32x4){0.f, 0.f, 0.f, 0.f};

    short8 af[2], afn[2];
    #pragma unroll
    for (int mt = 0; mt < 2; ++mt)
        af[mt] = *(const short8*)(act + (size_t)(m0 + mt * 16 + lo) * DPAD + hi * 8);
    stage(0, 0);
    stage(1, 1);
    asm volatile("s_waitcnt vmcnt(4)" ::: "memory");   // retire af + stage0
    __builtin_amdgcn_s_barrier();

    #pragma unroll
    for (int ks = 0; ks < 7; ++ks) {
        const int cur = ks % 3;
        if (ks < 6) {
            #pragma unroll
            for (int mt = 0; mt < 2; ++mt)
                afn[mt] = *(const short8*)(act + (size_t)(m0 + mt * 16 + lo) * DPAD
                                           + (ks + 1) * 32 + hi * 8);
        }
        if (ks < 5) stage(ks + 2, (ks + 2) % 3);

        #pragma unroll
        for (int nt = 0; nt < 14; ++nt) {
            int brow = nt * 16 + lo;
            short8 bf_ = *(const short8*)&WB[cur][brow * 32
                                                  + ((hi * 8) ^ (((brow >> 1) & 3) << 3))];
            acc[0][nt] = __builtin_amdgcn_mfma_f32_16x16x32_bf16(af[0], bf_, acc[0][nt], 0, 0, 0);
            acc[1][nt] = __builtin_amdgcn_mfma_f32_16x16x32_bf16(af[1], bf_, acc[1][nt], 0, 0, 0);
        }

        if (ks < 5) {
            asm volatile("s_waitcnt vmcnt(6)" ::: "memory");   // retire stage(ks+1)
            __builtin_amdgcn_s_barrier();
        } else if (ks == 5) {
            asm volatile("s_waitcnt vmcnt(2)" ::: "memory");   // retire stage(6)
            __builtin_amdgcn_s_barrier();
        }
        if (ks < 6) { af[0] = afn[0]; af[1] = afn[1]; }
    }

    const int bb = mblk >> 10;                 // batch (blocks never straddle)
    float inv_a = 1.f, corr = 0.f;
    if (actParts) {
        float mean = actParts[bb * 2] / LN_N;
        inv_a = rsqrtf(actParts[bb * 2 + 1] / LN_N - mean * mean + EPS);
        corr = mean * inv_a;
    }
    float mean_r = 0.f, inv_r = 1.f;
    if (resParts) {
        mean_r = resParts[bb * 2] / LN_N;
        inv_r = rsqrtf(resParts[bb * 2 + 1] / LN_N - mean_r * mean_r + EPS);
    }

    float s = 0.f, s2 = 0.f;
    #pragma unroll
    for (int mt = 0; mt < 2; ++mt) {
        #pragma unroll
        for (int nt = 0; nt < 14; ++nt) {
            const int n = nt * 16 + lo;
            const float bn = bias[n];
            const float cw = actParts ? csW[n] : 0.f;
            float v[4];
            #pragma unroll
            for (int r = 0; r < 4; ++r)
                v[r] = acc[mt][nt][r] * inv_a + bn - corr * cw;
            if (res) {
                #pragma unroll
                for (int r = 0; r < 4; ++r) {
                    int m = m0 + mt * 16 + hi * 4 + r;
                    v[r] += (bf2f(res[(size_t)m * DPAD + n]) - mean_r) * inv_r;
                }
            }
            if (doRelu)
                #pragma unroll
                for (int r = 0; r < 4; ++r) v[r] = fmaxf(v[r], 0.f);
            if (n >= DDIM)
                #pragma unroll
                for (int r = 0; r < 4; ++r) v[r] = 0.f;
            if (parts)
                #pragma unroll
                for (int r = 0; r < 4; ++r) { s += v[r]; s2 = fmaf(v[r], v[r], s2); }
            short4_t o4;
            #pragma unroll
            for (int r = 0; r < 4; ++r) o4[r] = f2bf(v[r]);
            #pragma unroll
            for (int r = 0; r < 4; ++r) {
                int m = m0 + mt * 16 + hi * 4 + r;
                out[(size_t)m * outStride + n] = o4[r];
            }
            if (pt && nt < 13) {
                const int sloc = (m0 + mt * 16 + hi * 4) & (SDIM - 1);
                *(short4_t*)(pt + ((size_t)bb * DPAD + n) * SDIM + sloc) = o4;
            }
        }
    }

    if (parts) {
        __shared__ float rs[4], rq[4];
        #pragma unroll
        for (int off = 32; off; off >>= 1) {
            s  += __shfl_down(s, off);
            s2 += __shfl_down(s2, off);
        }
        if (lane == 0) { rs[wave] = s; rq[wave] = s2; }
        __syncthreads();
        if (tid == 0) {
            atomicAdd(&parts[bb * 2],     rs[0] + rs[1] + rs[2] + rs[3]);
            atomicAdd(&parts[bb * 2 + 1], rq[0] + rq[1] + rq[2] + rq[3]);
        }
    }
}

// ---------------- fused FFN: out = relu(LN(act)@W1+b1)@W2 + b2 + LN(act) --------
// Ring-3 over 14 W-slices (W1 k0..6 = slices 0..6, W2 k0..6 = 7..13), uniform
// 16-chunk staging, counted vmcnt. Stage-1 iters: vmcnt(5) [retire stage(ks+1),
// leave afn(1)+stage(ks+2)(4)]. __syncthreads drains slices 7,8 before stage 2.
// Stage-2: vmcnt(4) [retire stage(j+1)], vmcnt(0) at j=12.
#define Y1S 232
__global__ __launch_bounds__(256, 2)
void ffn_bf(const short* __restrict__ act, const float* __restrict__ actParts,
            const float* __restrict__ csW1,
            const short* __restrict__ Wt1, const float* __restrict__ b1,
            const short* __restrict__ Wt2, const float* __restrict__ b2,
            short* __restrict__ out, float* __restrict__ parts)
{
    __shared__ short WB[3][WSLICE];   // 49152 B
    __shared__ short Y1[64 * Y1S];    // 29696 B   (total 78848 -> 2 blocks/CU)

    const int tid  = threadIdx.x;
    const int wave = tid >> 6, lane = tid & 63;
    const int lo   = lane & 15, hi = lane >> 4;
    const int mblk = blockIdx.x * 64;
    const int m0   = mblk + wave * 16;
    const int bb   = mblk >> 10;

    auto stageJ = [&](int j) {
        const short* W = (j < 7) ? Wt1 : Wt2;
        const int kk = (j < 7) ? j : j - 7;
        const int buf = j % 3;
        #pragma unroll
        for (int cc = 0; cc < 4; ++cc) {
            int c = wave + cc * 4;
            int row = c * 16 + (lane >> 2);
            int kc  = (lane & 3) ^ ((row >> 1) & 3);
            gload_lds16(W + (size_t)row * DPAD + kk * 32 + kc * 8,
                        &WB[buf][c * 512 + lane * 8]);
        }
    };

    const float mean_a = actParts[bb * 2] / LN_N;
    const float inv_a  = rsqrtf(actParts[bb * 2 + 1] / LN_N - mean_a * mean_a + EPS);
    const float corr   = mean_a * inv_a;

    // ---- stage 1: y1 = relu(LN(act)@W1 + b1) -> Y1 ----
    f32x4 acc[14];
    #pragma unroll
    for (int nt = 0; nt < 14; ++nt) acc[nt] = (f32x4){0.f, 0.f, 0.f, 0.f};

    short8 af = *(const short8*)(act + (size_t)(m0 + lo) * DPAD + hi * 8);
    short8 afn;
    stageJ(0);
    stageJ(1);
    asm volatile("s_waitcnt vmcnt(4)" ::: "memory");   // retire af + stage0
    __builtin_amdgcn_s_barrier();

    #pragma unroll
    for (int ks = 0; ks < 7; ++ks) {
        const int cur = ks % 3;
        if (ks < 6)
            afn = *(const short8*)(act + (size_t)(m0 + lo) * DPAD + (ks + 1) * 32 + hi * 8);
        stageJ(ks + 2);   // slices 2..8
        #pragma unroll
        for (int nt = 0; nt < 14; ++nt) {
            int brow = nt * 16 + lo;
            short8 bf_ = *(const short8*)&WB[cur][brow * 32
                                                  + ((hi * 8) ^ (((brow >> 1) & 3) << 3))];
            acc[nt] = __builtin_amdgcn_mfma_f32_16x16x32_bf16(af, bf_, acc[nt], 0, 0, 0);
        }
        if (ks < 6) {
            asm volatile("s_waitcnt vmcnt(5)" ::: "memory");   // retire stage(ks+1)
            __builtin_amdgcn_s_barrier();
            af = afn;
        }
    }

    // epilogue 1: bias + LN-colsum correction + relu -> Y1 (bf16)
    #pragma unroll
    for (int nt = 0; nt < 14; ++nt) {
        const int n = nt * 16 + lo;
        const float bn = b1[n];
        const float cw = csW1[n];
        #pragma unroll
        for (int r = 0; r < 4; ++r) {
            float v = fmaxf(acc[nt][r] * inv_a + bn - corr * cw, 0.f);
            Y1[(wave * 16 + hi * 4 + r) * Y1S + n] = f2bf(v);
        }
    }
    __syncthreads();   // Y1 visible; drains in-flight W2 slices 7,8

    // ---- stage 2: out = Y1 @ W2 + b2 + LN(act) ----
    #pragma unroll
    for (int nt = 0; nt < 14; ++nt) acc[nt] = (f32x4){0.f, 0.f, 0.f, 0.f};

    #pragma unroll
    for (int j = 7; j < 14; ++j) {
        const int cur = j % 3;
        if (j < 12) stageJ(j + 2);    // slices 9..13
        short8 a2 = *(const short8*)&Y1[(wave * 16 + lo) * Y1S + (j - 7) * 32 + hi * 8];
        #pragma unroll
        for (int nt = 0; nt < 14; ++nt) {
            int brow = nt * 16 + lo;
            short8 bf_ = *(const short8*)&WB[cur][brow * 32
                                                  + ((hi * 8) ^ (((brow >> 1) & 3) << 3))];
            acc[nt] = __builtin_amdgcn_mfma_f32_16x16x32_bf16(a2, bf_, acc[nt], 0, 0, 0);
        }
        if (j < 12)       asm volatile("s_waitcnt vmcnt(4)" ::: "memory");  // retire stage(j+1)
        else if (j == 12) asm volatile("s_waitcnt vmcnt(0)" ::: "memory");  // retire stage(13)
        if (j < 13) __builtin_amdgcn_s_barrier();
    }

    // epilogue 2: + b2 + LN(act) residual + stats -> out
    float s = 0.f, s2 = 0.f;
    #pragma unroll
    for (int nt = 0; nt < 14; ++nt) {
        const int n = nt * 16 + lo;
        const float bn = b2[n];
        float v[4];
        #pragma unroll
        for (int r = 0; r < 4; ++r) {
            int m = m0 + hi * 4 + r;
            v[r] = acc[nt][r] + bn + (bf2f(act[(size_t)m * DPAD + n]) - mean_a) * inv_a;
        }
        if (n >= DDIM)
            #pragma unroll
            for (int r = 0; r < 4; ++r) v[r] = 0.f;
        #pragma unroll
        for (int r = 0; r < 4; ++r) { s += v[r]; s2 = fmaf(v[r], v[r], s2); }
        #pragma unroll
        for (int r = 0; r < 4; ++r) {
            int m = m0 + hi * 4 + r;
            out[(size_t)m * DPAD + n] = f2bf(v[r]);
        }
    }

    {
        __shared__ float rs[4], rq[4];
        #pragma unroll
        for (int off = 32; off; off >>= 1) {
            s  += __shfl_down(s, off);
            s2 += __shfl_down(s2, off);
        }
        if (lane == 0) { rs[wave] = s; rq[wave] = s2; }
        __syncthreads();
        if (tid == 0) {
            atomicAdd(&parts[bb * 2],     rs[0] + rs[1] + rs[2] + rs[3]);
            atomicAdd(&parts[bb * 2 + 1], rq[0] + rq[1] + rq[2] + rq[3]);
        }
    }
}

// ---------------- fused MFMA flash attention (proven round-9/11 version) --------
__global__ __launch_bounds__(256, 2)
void attn_kernel(const short* __restrict__ pbf, const short* __restrict__ pt,
                 short* __restrict__ c, float qscale)
{
    __shared__ short Kbuf[2][7680];   // 32 x 232 (+pad)
    __shared__ short Vbuf[2][6656];   // 208 x 32 (col-xor-swizzled)

    const int bid = blockIdx.x;
    const int wg  = (bid & 7) * 64 + (bid >> 3);   // XCD chunk swizzle
    const int b   = wg >> 3;
    const int q0  = (wg & 7) * 128;

    const int tid  = threadIdx.x;
    const int wave = tid >> 6;
    const int lane = tid & 63;
    const int lo   = lane & 15;
    const int hi   = lane >> 4;

    const short* pb  = pbf + (size_t)b * SDIM * PSTRIDE;
    const short* ptb = pt  + (size_t)b * DPAD * SDIM;

    auto stage = [&](int kt2, int bufIdx) {
        const short* ks = pb + (size_t)kt2 * 32 * PSTRIDE + lane * 8;
        #pragma unroll
        for (int i = 0; i < 15; ++i)
            gload_lds16(ks + i * 512, &Kbuf[bufIdx][i * 512]);
        #pragma unroll
        for (int i = 0; i < 13; ++i) {
            int e = i * 512 + lane * 8;
            int d = e >> 5;
            int cc = (e & 31) ^ (((d >> 1) & 3) << 3);
            gload_lds16(ptb + (size_t)d * SDIM + kt2 * 32 + cc, &Vbuf[bufIdx][i * 512]);
        }
    };

    short8 qf[2][7];
    #pragma unroll
    for (int qt = 0; qt < 2; ++qt)
        #pragma unroll
        for (int ks = 0; ks < 7; ++ks) {
            short8 q = *(const short8*)(pb + (size_t)(q0 + wave * 32 + qt * 16 + lo) * PSTRIDE
                                        + ks * 32 + hi * 8);
            short8 qs;
            #pragma unroll
            for (int j = 0; j < 8; ++j) qs[j] = f2bf(bf2f(q[j]) * qscale);
            qf[qt][ks] = qs;
        }

    f32x4 o[2][13];
    float m[2], ell[2];
    #pragma unroll
    for (int qt = 0; qt < 2; ++qt) {
        #pragma unroll
        for (int n = 0; n < 13; ++n) o[qt][n] = (f32x4){0.f, 0.f, 0.f, 0.f};
        m[qt] = -1e30f; ell[qt] = 0.f;
    }

    if (wave == 0) stage(0, 0);
    __syncthreads();

    for (int kt = 0; kt < 32; ++kt) {
        const int cur = kt & 1;
        if (kt < 31 && wave == ((kt + 1) & 3)) stage(kt + 1, cur ^ 1);

        f32x4 sacc[2][2];
        #pragma unroll
        for (int qt = 0; qt < 2; ++qt)
            #pragma unroll
            for (int t = 0; t < 2; ++t) sacc[qt][t] = (f32x4){0.f, 0.f, 0.f, 0.f};
        __builtin_amdgcn_s_setprio(1);
        #pragma unroll
        for (int t = 0; t < 2; ++t)
            #pragma unroll
            for (int ks = 0; ks < 7; ++ks) {
                short8 kf = *(const short8*)(&Kbuf[cur][(t * 16 + lo) * PSTRIDE + ks * 32 + hi * 8]);
                sacc[0][t] = __builtin_amdgcn_mfma_f32_16x16x32_bf16(kf, qf[0][ks], sacc[0][t], 0, 0, 0);
                sacc[1][t] = __builtin_amdgcn_mfma_f32_16x16x32_bf16(kf, qf[1][ks], sacc[1][t], 0, 0, 0);
            }
        __builtin_amdgcn_s_setprio(0);

        short8 pa[2];
        #pragma unroll
        for (int qt = 0; qt < 2; ++qt) {
            float mx = fmaxf(fmaxf(fmaxf(sacc[qt][0][0], sacc[qt][0][1]),
                                   fmaxf(sacc[qt][0][2], sacc[qt][0][3])),
                             fmaxf(fmaxf(sacc[qt][1][0], sacc[qt][1][1]),
                                   fmaxf(sacc[qt][1][2], sacc[qt][1][3])));
            mx = fmaxf(mx, __shfl_xor(mx, 16));
            mx = fmaxf(mx, __shfl_xor(mx, 32));
            if (__any(mx > m[qt] + 11.5f)) {          // T13 defer-max (log2 units)
                float mn = fmaxf(m[qt], mx);
                float al = exp2f(m[qt] - mn);
                m[qt] = mn; ell[qt] *= al;
                float alr[4];
                #pragma unroll
                for (int r = 0; r < 4; ++r) alr[r] = __shfl(al, hi * 4 + r);
                #pragma unroll
                for (int n = 0; n < 13; ++n)
                    #pragma unroll
                    for (int r = 0; r < 4; ++r) o[qt][n][r] *= alr[r];
            }
            float p[2][4]; float rsum = 0.f;
            #pragma unroll
            for (int t = 0; t < 2; ++t)
                #pragma unroll
                for (int r = 0; r < 4; ++r) {
                    p[t][r] = exp2f(sacc[qt][t][r] - m[qt]);
                    rsum += p[t][r];
                }
            rsum += __shfl_xor(rsum, 16);
            rsum += __shfl_xor(rsum, 32);
            ell[qt] += rsum;
            unsigned pk01_0 = cvtpk_bf16(p[0][0], p[0][1]);
            unsigned pk23_0 = cvtpk_bf16(p[0][2], p[0][3]);
            unsigned pk01_1 = cvtpk_bf16(p[1][0], p[1][1]);
            unsigned pk23_1 = cvtpk_bf16(p[1][2], p[1][3]);
            const int srcA = lo + ((hi & 1) * 2) * 16;
            const int srcB = srcA + 16;
            int a0 = __shfl((int)pk01_0, srcA), a1 = __shfl((int)pk01_1, srcA);
            int b0 = __shfl((int)pk23_0, srcA), b1 = __shfl((int)pk23_1, srcA);
            int c0 = __shfl((int)pk01_0, srcB), c1 = __shfl((int)pk01_1, srcB);
            int d0 = __shfl((int)pk23_0, srcB), d1 = __shfl((int)pk23_1, srcB);
            const bool thi = (hi >> 1) != 0;
            union { short8 s; int u[4]; } pu;
            pu.u[0] = thi ? a1 : a0;
            pu.u[1] = thi ? b1 : b0;
            pu.u[2] = thi ? c1 : c0;
            pu.u[3] = thi ? d1 : d0;
            pa[qt] = pu.s;
        }

        __builtin_amdgcn_s_setprio(1);
        #pragma unroll
        for (int n = 0; n < 13; ++n) {
            int d = n * 16 + lo;
            int addr = d * 32 + ((hi * 8) ^ (((d >> 1) & 3) << 3));
            short8 vf = *(const short8*)(&Vbuf[cur][addr]);
            o[0][n] = __builtin_amdgcn_mfma_f32_16x16x32_bf16(pa[0], vf, o[0][n], 0, 0, 0);
            o[1][n] = __builtin_amdgcn_mfma_f32_16x16x32_bf16(pa[1], vf, o[1][n], 0, 0, 0);
        }
        __builtin_amdgcn_s_setprio(0);

        __syncthreads();
    }

    #pragma unroll
    for (int qt = 0; qt < 2; ++qt) {
        float inv_l = 1.f / ell[qt];
        float invr[4];
        #pragma unroll
        for (int r = 0; r < 4; ++r) invr[r] = __shfl(inv_l, hi * 4 + r);
        #pragma unroll
        for (int n = 0; n < 13; ++n) {
            int dcol = n * 16 + lo;
            #pragma unroll
            for (int r = 0; r < 4; ++r) {
                size_t row = (size_t)b * SDIM + q0 + wave * 32 + qt * 16 + hi * 4 + r;
                c[row * DPAD + dcol] = f2bf(o[qt][n][r] * invr[r]);
            }
        }
        #pragma unroll
        for (int r = 0; r < 4; ++r) {
            size_t row = (size_t)b * SDIM + q0 + wave * 32 + qt * 16 + hi * 4 + r;
            c[row * DPAD + 208 + lo] = 0;
        }
    }
}

// ---------------- final: normalize row S-1 only + head ----------------
__global__ void final_kernel(const short* __restrict__ y, const float* __restrict__ parts,
                             const float* __restrict__ Wd, const float* __restrict__ bd,
                             float* __restrict__ out)
{
    const int b = blockIdx.x;
    const float sum = parts[b * 2], sq = parts[b * 2 + 1];
    const float mean = sum / LN_N;
    const float inv  = rsqrtf(sq / LN_N - mean * mean + EPS);
    __shared__ float hrow[DDIM];
    const short* row = y + ((size_t)b * SDIM + SDIM - 1) * DPAD;
    for (int d = threadIdx.x; d < DDIM; d += blockDim.x)
        hrow[d] = (bf2f(row[d]) - mean) * inv;
    __syncthreads();
    if (threadIdx.x < CDIM) {
        float acc = bd[threadIdx.x];
        for (int d = 0; d < DDIM; ++d)
            acc = fmaf(hrow[d], Wd[(size_t)d * CDIM + threadIdx.x], acc);
        out[(size_t)b * CDIM + threadIdx.x] = acc;
    }
}

extern "C" void kernel_launch(void* const* d_in, const int* in_sizes, int n_in,
                              void* d_out, int out_size, void* d_ws, size_t ws_size,
                              hipStream_t stream)
{
    const int*   x     = (const int*)  d_in[0];
    const float* embed = (const float*)d_in[1];
    const float* pos   = (const float*)d_in[2];
    const float* Wp    = (const float*)d_in[3];
    const float* bp    = (const float*)d_in[4];
    const float* Wm    = (const float*)d_in[5];
    const float* bm    = (const float*)d_in[6];
    const float* W1    = (const float*)d_in[7];
    const float* b1    = (const float*)d_in[8];
    const float* W2    = (const float*)d_in[9];
    const float* b2    = (const float*)d_in[10];
    const float* Wd    = (const float*)d_in[11];
    const float* bd    = (const float*)d_in[12];
    float* out = (float*)d_out;

    const size_t HB = (size_t)BDIM * SDIM * DPAD;     // 14,680,064 bf16 elems
    const size_t PB = (size_t)BDIM * SDIM * PSTRIDE;  // p_bf with stride 232
    const size_t WTSZ = (size_t)WROWS * DPAD;         // padded weight buffers

    short* h_bf  = (short*)d_ws;
    short* p_bf  = h_bf  + HB;
    short* pt    = p_bf  + PB;
    short* cb_bf = pt    + HB;
    short* yA    = cb_bf + HB;
    short* yB    = yA    + HB;
    short* WtP   = yB + HB;
    short* WtM   = WtP + WTSZ;
    short* Wt1   = WtM + WTSZ;
    short* Wt2   = Wt1 + WTSZ;
    float* bpP   = (float*)(Wt2 + WTSZ);
    float* bmP   = bpP + DPAD;
    float* b1P   = bmP + DPAD;
    float* b2P   = b1P + DPAD;
    float* csP   = b2P + DPAD;
    float* cs1   = csP + DPAD;
    float* parts = cs1 + DPAD;                        // 4 x 64 x 2 floats
    const size_t need = (size_t)((char*)(parts + 4 * BDIM * 2) - (char*)d_ws);
    if (ws_size < need) return;

    float* pA1 = parts;
    float* pB1 = parts + BDIM * 2;
    float* pA2 = parts + 2 * BDIM * 2;
    float* pB2 = parts + 3 * BDIM * 2;

    prep_embed_kernel<<<dim3(PREP_BLOCKS + 2048), dim3(256), 0, stream>>>(
        x, embed, pos, Wp, bp, Wm, bm, W1, b1, W2, b2,
        WtP, WtM, Wt1, Wt2, bpP, bmP, b1P, b2P, csP, cs1, h_bf, parts);

    const float qscale = 1.44269504f / sqrtf((float)DDIM);

    // stack 1
    gemm_bf<<<dim3(512), dim3(256), 0, stream>>>(h_bf, nullptr, WtP, bpP, nullptr,
                                                 nullptr, nullptr, p_bf, pt, nullptr, 0, PSTRIDE);
    attn_kernel<<<dim3(512), dim3(256), 0, stream>>>(p_bf, pt, cb_bf, qscale);
    gemm_bf<<<dim3(512), dim3(256), 0, stream>>>(cb_bf, nullptr, WtM, bmP, nullptr,
                                                 h_bf, nullptr, yA, nullptr, pA1, 0, DPAD);
    ffn_bf<<<dim3(1024), dim3(256), 0, stream>>>(yA, pA1, cs1, Wt1, b1P, Wt2, b2P, yB, pB1);
    // stack 2
    gemm_bf<<<dim3(512), dim3(256), 0, stream>>>(yB, pB1, WtP, bpP, csP,
                                                 nullptr, nullptr, p_bf, pt, nullptr, 0, PSTRIDE);
    attn_kernel<<<dim3(512), dim3(256), 0, stream>>>(p_bf, pt, cb_bf, qscale);
    gemm_bf<<<dim3(512), dim3(256), 0, stream>>>(cb_bf, nullptr, WtM, bmP, nullptr,
                                                 yB, pB1, h_bf, nullptr, pA2, 0, DPAD);
    ffn_bf<<<dim3(1024), dim3(256), 0, stream>>>(h_bf, pA2, cs1, Wt1, b1P, Wt2, b2P, yA, pB2);
    final_kernel<<<dim3(BDIM), dim3(64), 0, stream>>>(yA, pB2, Wd, bd, out);
}